// Round 2
// baseline (11.103 us; speedup 1.0000x reference)
//
#include <hip/hip_runtime.h>

#define BB 8
#define DD 65536
#define GG 1024
#define OUTN 4096

// ---------------- Kernel A: one wave per 64 d's, no LDS, no barrier ----------------
__global__ __launch_bounds__(64) void ril_partials(
    const float* __restrict__ x,        // (8, 65536)
    const float* __restrict__ weights,  // (1024*65536,)
    const float* __restrict__ min_vals, // (1024,)
    const float* __restrict__ max_vals, // (1024,)
    const int* __restrict__ start_pos,  // (1024,)
    const int* __restrict__ offsets,    // (1024,)
    const int* __restrict__ sizes,      // (1024,)
    float* __restrict__ partials,       // (1024,)
    int wlen)
{
    const int t = threadIdx.x;
    const int d = blockIdx.x * 64 + t;

    // Issue all 8 x-row loads immediately (independent, coalesced).
    float x0 = x[0 * DD + d];
    float x1 = x[1 * DD + d];
    float x2 = x[2 * DD + d];
    float x3 = x[3 * DD + d];
    float x4 = x[4 * DD + d];
    float x5 = x[5 * DD + d];
    float x6 = x[6 * DD + d];
    float x7 = x[7 * DD + d];

    // Scale factors for the analytic bin guess (L1-broadcast loads).
    const float m0    = min_vals[0];
    const float mlast = min_vals[GG - 1];

    const float v = (((x0 + x1) + (x2 + x3)) + ((x4 + x5) + (x6 + x7))) * 0.125f;

    // Analytic guess for g = searchsorted(min_vals, v, 'right') - 1,
    // then EXACT fixup (preserves reference semantics for any min_vals).
    float inv = (mlast > m0) ? (float)(GG - 1) / (mlast - m0) : 0.0f;
    float gf = (v - m0) * inv;
    gf = fminf(fmaxf(gf, -1.0f), (float)(GG - 1));
    int gi = (int)floorf(gf);
    // invariant target: largest i with min_vals[i] <= v, or -1 if none
    while (gi + 1 < GG && min_vals[gi + 1] <= v) ++gi;
    while (gi >= 0 && min_vals[gi] > v) --gi;

    const int g  = gi;
    const int gc = min(max(g, 0), GG - 1);

    // Independent L1-hot table lookups (one latency round).
    const float mn = min_vals[gc];
    const float mx = max_vals[gc];
    const int   sp = start_pos[gc];
    const int   of = offsets[gc];
    const int   sz = sizes[gc];

    const bool in_range = (g >= 0) && (v >= mn) && (v <= mx);
    const int  pos      = d - sp;
    const bool valid    = in_range && (pos >= 0) && (pos < sz);

    int widx = of + pos;
    widx = min(max(widx, 0), wlen - 1);
    const float w = valid ? weights[widx] : 0.0f;

    float p = v * w;

    // wave64 shuffle reduce (fixed order -> deterministic)
#pragma unroll
    for (int off = 32; off > 0; off >>= 1) p += __shfl_down(p, off);

    if (t == 0) partials[blockIdx.x] = p;
}

// ---------------- Kernel B: reduce 1024 partials, write output (float4) ----------------
__global__ __launch_bounds__(256) void ril_finalize(
    const float* __restrict__ partials, // (1024,)
    const int* __restrict__ out_mask,   // (4096,) bool pushed as int32
    float* __restrict__ out)            // (8*4096,)
{
    const int t = threadIdx.x;

    float p = (partials[t] + partials[t + 256]) + (partials[t + 512] + partials[t + 768]);
#pragma unroll
    for (int off = 32; off > 0; off >>= 1) p += __shfl_down(p, off);

    __shared__ float s_wsum[4];
    __shared__ float s_total;
    if ((t & 63) == 0) s_wsum[t >> 6] = p;
    __syncthreads();
    if (t == 0) s_total = (s_wsum[0] + s_wsum[1]) + (s_wsum[2] + s_wsum[3]);
    __syncthreads();
    const float s = s_total;

    // 32 blocks * 256 threads * 4 floats = 32768 outputs
    const int q = (blockIdx.x * 256 + t) * 4;
    float4 val = {0.0f, 0.0f, 0.0f, 0.0f};
    if (q < OUTN) {  // only row 0 (first 4096) can be nonzero
        const int4 m = *reinterpret_cast<const int4*>(&out_mask[q]);
        val.x = m.x ? s : 0.0f;
        val.y = m.y ? s : 0.0f;
        val.z = m.z ? s : 0.0f;
        val.w = m.w ? s : 0.0f;
    }
    *reinterpret_cast<float4*>(&out[q]) = val;
}

extern "C" void kernel_launch(void* const* d_in, const int* in_sizes, int n_in,
                              void* d_out, int out_size, void* d_ws, size_t ws_size,
                              hipStream_t stream) {
    const float* x        = (const float*)d_in[0];
    const float* weights  = (const float*)d_in[1];
    const float* min_vals = (const float*)d_in[2];
    const float* max_vals = (const float*)d_in[3];
    const int*   start_p  = (const int*)d_in[4];
    const int*   offsets  = (const int*)d_in[5];
    const int*   sizes    = (const int*)d_in[6];
    const int*   out_mask = (const int*)d_in[7];
    float* out = (float*)d_out;
    float* partials = (float*)d_ws;   // 1024 floats; every slot written each call

    const int wlen = in_sizes[1];

    ril_partials<<<DD / 64, 64, 0, stream>>>(
        x, weights, min_vals, max_vals, start_p, offsets, sizes, partials, wlen);

    ril_finalize<<<(BB * OUTN) / (256 * 4), 256, 0, stream>>>(partials, out_mask, out);
}